// Round 1
// baseline (1536.082 us; speedup 1.0000x reference)
//
#include <hip/hip_runtime.h>
#include <hip/hip_bf16.h>

// MyRnn: h_t = tanh(emb[idx_t] @ W_xh + b_h + h_{t-1} @ W_hh), 80 steps,
// out = sigmoid(h_80 @ W_out + b_out).
//
// Architecture: batch-parallel persistent kernel. 256 blocks x 512 threads
// (8 waves), one block per CU, 8 batch rows per block (M padded 8->16 for
// 16x16x32 bf16 MFMA). Weights are REGISTER-STATIONARY: wave w owns cols
// [64w,64w+64) of W_hh (64 bf16x8 B-frags = 256 regs -> AGPRs via
// launch_bounds(512,2)) and of W_xh (K padded 100->128, 16 frags = 64 regs).
// h round-trips through XOR-swizzled LDS (bf16) each step; x for step t+1 is
// staged during step t; ONE __syncthreads per step.

#define BATCH   2048
#define T_LEN   80
#define EMB_D   100
#define UNITS   512
#define ROWS    8
#define NBLK    (BATCH / ROWS)   // 256
#define NTHR    512
#define NT      4                // n-tiles (16 cols) per wave
#define KSH     16               // K-steps for W_hh (512/32)
#define KSX     4                // K-steps for W_xh (128/32, zero-padded)

typedef __bf16 bf16x8 __attribute__((ext_vector_type(8)));
typedef float  f32x4  __attribute__((ext_vector_type(4)));

__device__ __forceinline__ float fast_tanh(float x) {
    // tanh(x) = 1 - 2/(1+exp(2x)); exp(2x) = exp2(x * 2*log2(e))
    float e = __builtin_amdgcn_exp2f(x * 2.8853900817779268f);
    return 1.0f - 2.0f * __builtin_amdgcn_rcpf(1.0f + e);
}

__global__ __launch_bounds__(NTHR, 2)
void rnn_kernel(const int*   __restrict__ inputs,   // [2048][80]
                const float* __restrict__ emb,      // [35000][100]
                const float* __restrict__ Wxh,      // [100][512]
                const float* __restrict__ Whh,      // [512][512]
                const float* __restrict__ bh,       // [512]
                const float* __restrict__ Wout,     // [512]
                const float* __restrict__ bout,     // [1]
                float*       __restrict__ out)      // [2048]
{
    // h: 16 rows (8 real + 8 zero-pad) x 512 bf16, 16B-chunk XOR swizzle:
    //   elem(m, k) = m*512 + (((k>>3) ^ (m&7))<<3) + (k&7)
    // x: 16 rows x 128 (100 real + pad) bf16, same swizzle with row stride 128.
    __shared__ alignas(16) __bf16 hbuf[2][16 * UNITS];
    __shared__ alignas(16) __bf16 xbuf[2][16 * 128];

    const int tid  = threadIdx.x;
    const int wave = tid >> 6;       // 0..7
    const int lane = tid & 63;
    const int q    = lane >> 4;      // MFMA quad
    const int ln   = lane & 15;      // MFMA row/col within tile
    const int e7   = ln & 7;
    const int qa   = q ^ (e7 & 3);   // precomputed swizzle pieces:
    const int kx   = e7 >> 2;        // chunk c=(ks<<2)|q -> c^e7 = ((ks^kx)<<2)|qa
    const int r0   = blockIdx.x * ROWS;

    // ---------------- stationary weights ----------------
    bf16x8 whh[KSH][NT];   // B-frag: B[k][n], n = ln, k = q*8 + j (+32*ks)
    bf16x8 wxh[KSX][NT];
    float  bhv[NT];

    #pragma unroll
    for (int nt = 0; nt < NT; ++nt) {
        const int col = (wave << 6) + (nt << 4) + ln;
        bhv[nt] = bh[col];
        #pragma unroll
        for (int ks = 0; ks < KSH; ++ks) {
            const int kb = (ks << 5) + (q << 3);
            bf16x8 f;
            #pragma unroll
            for (int j = 0; j < 8; ++j)
                f[j] = (__bf16)Whh[(kb + j) * UNITS + col];
            whh[ks][nt] = f;
        }
        #pragma unroll
        for (int ks = 0; ks < KSX; ++ks) {
            const int kb = (ks << 5) + (q << 3);
            bf16x8 f;
            #pragma unroll
            for (int j = 0; j < 8; ++j) {
                const int k = kb + j;
                f[j] = (k < EMB_D) ? (__bf16)Wxh[k * UNITS + col] : (__bf16)0.0f;
            }
            wxh[ks][nt] = f;
        }
    }

    // ---------------- zero LDS (h0 = 0, pad rows, pad cols) ----------------
    {
        int4 z; z.x = z.y = z.z = z.w = 0;
        int4* hp = (int4*)&hbuf[0][0];
        #pragma unroll 1
        for (int i = tid; i < 2048; i += NTHR) hp[i] = z;   // 2*16*512*2B /16B
        int4* xp = (int4*)&xbuf[0][0];
        xp[tid] = z;                                        // 2*16*128*2B /16B = 512
    }
    __syncthreads();

    // stage embedded x_t (bf16, swizzled) — one wave per batch row
    auto stage = [&](int t, __bf16* xb) {
        const int r = wave;
        const int idxv = inputs[(r0 + r) * T_LEN + t];
        const float* er = emb + (size_t)idxv * EMB_D;
        const int k0 = lane;   // < 100 always
        xb[(r << 7) + ((((k0 >> 3) ^ r) << 3) | (k0 & 7))] = (__bf16)er[k0];
        const int k1 = lane + 64;
        if (k1 < EMB_D)
            xb[(r << 7) + ((((k1 >> 3) ^ r) << 3) | (k1 & 7))] = (__bf16)er[k1];
    };

    auto step = [&](const __bf16* hb_r, const __bf16* xb_r, __bf16* hb_w) {
        f32x4 acc[NT];
        #pragma unroll
        for (int nt = 0; nt < NT; ++nt) {
            f32x4 a = {bhv[nt], bhv[nt], bhv[nt], bhv[nt]};
            acc[nt] = a;
        }
        const int xbase = (ln << 7) + (qa << 3);
        #pragma unroll
        for (int ks = 0; ks < KSX; ++ks) {
            bf16x8 a = *(const bf16x8*)&xb_r[xbase + ((ks ^ kx) << 5)];
            #pragma unroll
            for (int nt = 0; nt < NT; ++nt)
                acc[nt] = __builtin_amdgcn_mfma_f32_16x16x32_bf16(a, wxh[ks][nt], acc[nt], 0, 0, 0);
        }
        const int hbase = (ln << 9) + (qa << 3);
        #pragma unroll
        for (int ks = 0; ks < KSH; ++ks) {
            bf16x8 a = *(const bf16x8*)&hb_r[hbase + ((ks ^ kx) << 5)];
            #pragma unroll
            for (int nt = 0; nt < NT; ++nt)
                acc[nt] = __builtin_amdgcn_mfma_f32_16x16x32_bf16(a, whh[ks][nt], acc[nt], 0, 0, 0);
        }
        // C/D layout: col = ln, row = 4*q + i. Real rows are 0..7 (q<2).
        if (q < 2) {
            #pragma unroll
            for (int nt = 0; nt < NT; ++nt) {
                const int c = (wave << 3) + (nt << 1) + (ln >> 3);  // col>>3
                #pragma unroll
                for (int i = 0; i < 4; ++i) {
                    const int row = (q << 2) + i;
                    hb_w[(row << 9) + (((c ^ row) << 3) | (ln & 7))] =
                        (__bf16)fast_tanh(acc[nt][i]);
                }
            }
        }
    };

    stage(0, xbuf[0]);
    __syncthreads();

    #pragma unroll 1
    for (int t = 0; t < T_LEN; t += 2) {
        stage(t + 1, xbuf[1]);                       // t+1 <= 79
        step(hbuf[0], xbuf[0], hbuf[1]);
        __syncthreads();
        if (t + 2 < T_LEN) stage(t + 2, xbuf[0]);
        step(hbuf[1], xbuf[1], hbuf[0]);
        __syncthreads();
    }
    // h_last now in hbuf[0], rows 0..7

    // ---------------- output head: one wave per row ----------------
    {
        const int m = wave;
        const bf16x8 hv = *(const bf16x8*)&hbuf[0][(m << 9) + ((lane ^ m) << 3)];
        float s = 0.0f;
        #pragma unroll
        for (int j = 0; j < 8; ++j)
            s += (float)hv[j] * Wout[(lane << 3) + j];
        #pragma unroll
        for (int off = 32; off > 0; off >>= 1)
            s += __shfl_down(s, off, 64);
        if (lane == 0) {
            const float logit = s + bout[0];
            out[r0 + m] = __builtin_amdgcn_rcpf(
                1.0f + __builtin_amdgcn_exp2f(-logit * 1.4426950408889634f));
        }
    }
}

extern "C" void kernel_launch(void* const* d_in, const int* in_sizes, int n_in,
                              void* d_out, int out_size, void* d_ws, size_t ws_size,
                              hipStream_t stream) {
    rnn_kernel<<<dim3(NBLK), dim3(NTHR), 0, stream>>>(
        (const int*)d_in[0],    // inputs
        (const float*)d_in[1],  // emb_table
        (const float*)d_in[2],  // W_xh
        (const float*)d_in[3],  // W_hh
        (const float*)d_in[4],  // b_h
        (const float*)d_in[5],  // W_out
        (const float*)d_in[6],  // b_out
        (float*)d_out);
}

// Round 2
// 1106.804 us; speedup vs baseline: 1.3879x; 1.3879x over previous
//
#include <hip/hip_runtime.h>
#include <hip/hip_bf16.h>

// MyRnn: h_t = tanh(emb[idx_t] @ W_xh + b_h + h_{t-1} @ W_hh), 80 steps,
// out = sigmoid(h_80 @ W_out + b_out).
//
// R2 architecture: 128 blocks x 512 thr (8 waves), 16 REAL batch rows per
// block (no M-pad waste). launch_bounds(512,1) -> 256-VGPR cap, 1 block/CU.
// Prep kernel writes transposed bf16 weight tables into d_ws:
//   Wt[512 n][512 k], Xt[512 n][128 k] (k>=100 zero) -- every MFMA B-frag is
//   one aligned 16B load. Wave w owns cols [64w,64w+64): W_xh (4 ksteps) +
//   W_hh ksteps 0..RKS-1 resident in regs; ksteps RKS..15 streamed from L2
//   (Wt is L2-resident, 512KB) direct-to-VGPR each step, 2-deep pipeline,
//   latency hidden behind the resident MFMAs. h double-buffers through
//   XOR-swizzled LDS; ONE __syncthreads per step.

#define T_LEN   80
#define EMB_D   100
#define UNITS   512
#define ROWS    16
#define NBLK    128
#define NTHR    512
#define NT      4                // n-tiles (16 cols) per wave
#define KSH     16               // K-steps for W_hh (512/32)
#define KSX     4                // K-steps for W_xh (128/32, zero-padded)
#define RKS     6                // W_hh ksteps resident in registers

typedef __bf16 bf16x8 __attribute__((ext_vector_type(8)));
typedef float  f32x4  __attribute__((ext_vector_type(4)));

__device__ __forceinline__ float fast_tanh(float x) {
    float e = __builtin_amdgcn_exp2f(x * 2.8853900817779268f);
    return 1.0f - 2.0f * __builtin_amdgcn_rcpf(1.0f + e);
}

// ---- prep: transpose + bf16-cast weights into d_ws ----
// blocks 0..255:   Whh f32[512k][512n] -> Wt bf16[512n][512k]
// blocks 256..319: Wxh f32[100k][512n] -> Xt bf16[512n][128k] (pad k -> 0)
__global__ void prep_kernel(const float* __restrict__ Whh,
                            const float* __restrict__ Wxh,
                            __bf16* __restrict__ Wt, __bf16* __restrict__ Xt) {
    __shared__ float tile[32][33];
    const int tx = threadIdx.x & 31, ty = threadIdx.x >> 5;  // 32x8
    const int b = blockIdx.x;
    if (b < 256) {
        const int k0 = (b & 15) * 32, n0 = (b >> 4) * 32;
        #pragma unroll
        for (int i = 0; i < 4; ++i)
            tile[ty + 8 * i][tx] = Whh[(k0 + ty + 8 * i) * UNITS + n0 + tx];
        __syncthreads();
        #pragma unroll
        for (int i = 0; i < 4; ++i) {
            const int n = ty + 8 * i;
            Wt[(n0 + n) * UNITS + k0 + tx] = (__bf16)tile[tx][n];
        }
    } else {
        const int bb = b - 256;
        const int k0 = (bb & 3) * 32, n0 = (bb >> 2) * 32;
        #pragma unroll
        for (int i = 0; i < 4; ++i) {
            const int k = k0 + ty + 8 * i;
            tile[ty + 8 * i][tx] = (k < EMB_D) ? Wxh[k * UNITS + n0 + tx] : 0.0f;
        }
        __syncthreads();
        #pragma unroll
        for (int i = 0; i < 4; ++i) {
            const int n = ty + 8 * i;
            Xt[(n0 + n) * 128 + k0 + tx] = (__bf16)tile[tx][n];
        }
    }
}

__global__ __launch_bounds__(NTHR, 1)
void rnn_kernel(const int*   __restrict__ inputs,   // [2048][80]
                const float* __restrict__ emb,      // [35000][100]
                const float* __restrict__ bh,       // [512]
                const float* __restrict__ Wout,     // [512]
                const float* __restrict__ bout,     // [1]
                const __bf16* __restrict__ Wt,      // [512][512] (ws)
                const __bf16* __restrict__ Xt,      // [512][128] (ws)
                float*       __restrict__ out)      // [2048]
{
    // h: 16 rows x 512 bf16, 16B-chunk XOR swizzle:
    //   elem(m,k) = m*512 + (((k>>3) ^ (m&7))<<3) + (k&7)
    // x: 16 rows x 128 bf16, same swizzle, row stride 128.
    __shared__ alignas(16) __bf16 hbuf[2][16 * UNITS];
    __shared__ alignas(16) __bf16 xbuf[2][16 * 128];

    const int tid  = threadIdx.x;
    const int wave = tid >> 6;       // 0..7
    const int lane = tid & 63;
    const int q    = lane >> 4;      // MFMA quad
    const int ln   = lane & 15;
    const int e7   = ln & 7;
    const int qa   = q ^ (e7 & 3);
    const int kx   = e7 >> 2;
    const int q8   = q << 3;
    const int r0   = blockIdx.x * ROWS;

    // per-nt column offsets into Wt/Xt
    int coff[NT], cxff[NT];
    float bhv[NT];
    #pragma unroll
    for (int nt = 0; nt < NT; ++nt) {
        const int c = (wave << 6) + (nt << 4) + ln;
        coff[nt] = c * UNITS;
        cxff[nt] = c * 128;
        bhv[nt]  = bh[c];
    }

    // resident B-frags (read from prep output; prior kernel on same stream)
    bf16x8 whh[RKS][NT];
    bf16x8 wxh[KSX][NT];
    #pragma unroll
    for (int nt = 0; nt < NT; ++nt) {
        #pragma unroll
        for (int ks = 0; ks < RKS; ++ks)
            whh[ks][nt] = *(const bf16x8*)(Wt + coff[nt] + (ks << 5) + q8);
        #pragma unroll
        for (int ks = 0; ks < KSX; ++ks)
            wxh[ks][nt] = *(const bf16x8*)(Xt + cxff[nt] + (ks << 5) + q8);
    }

    // zero LDS (h0 = 0; x pad cols k>=100 stay 0 forever)
    {
        int4 z; z.x = z.y = z.z = z.w = 0;
        int4* hp = (int4*)&hbuf[0][0];
        #pragma unroll
        for (int i = 0; i < 4; ++i) hp[tid + i * NTHR] = z;   // 32KB
        int4* xp = (int4*)&xbuf[0][0];
        xp[tid] = z;                                          // 8KB
    }
    __syncthreads();

    // stage embedded x_t (bf16, swizzled); wave w does rows w and w+8
    auto stage = [&](int t, __bf16* xb) {
        #pragma unroll
        for (int rr = 0; rr < 2; ++rr) {
            const int r = wave + (rr << 3);
            const int idxv = inputs[(r0 + r) * T_LEN + t];
            const float* er = emb + (size_t)idxv * EMB_D;
            const int k0 = lane;          // < 100 always
            xb[(r << 7) + ((((k0 >> 3) ^ (r & 7)) << 3) | (k0 & 7))] = (__bf16)er[k0];
            const int k1 = lane + 64;
            if (k1 < EMB_D)
                xb[(r << 7) + ((((k1 >> 3) ^ (r & 7)) << 3) | (k1 & 7))] = (__bf16)er[k1];
        }
    };

    auto step = [&](const __bf16* hb_r, const __bf16* xb_r, __bf16* hb_w) {
        // issue first two streamed ksteps ASAP (L2 hits; no dependence on h)
        bf16x8 sB[2][NT];
        #pragma unroll
        for (int nt = 0; nt < NT; ++nt)
            sB[0][nt] = *(const bf16x8*)(Wt + coff[nt] + (RKS << 5) + q8);
        #pragma unroll
        for (int nt = 0; nt < NT; ++nt)
            sB[1][nt] = *(const bf16x8*)(Wt + coff[nt] + ((RKS + 1) << 5) + q8);

        f32x4 acc[NT];
        #pragma unroll
        for (int nt = 0; nt < NT; ++nt) {
            f32x4 a = {bhv[nt], bhv[nt], bhv[nt], bhv[nt]};
            acc[nt] = a;
        }

        // x contribution (resident wxh)
        const int xbase = (ln << 7) + (qa << 3);
        #pragma unroll
        for (int ks = 0; ks < KSX; ++ks) {
            bf16x8 a = *(const bf16x8*)&xb_r[xbase + ((ks ^ kx) << 5)];
            #pragma unroll
            for (int nt = 0; nt < NT; ++nt)
                acc[nt] = __builtin_amdgcn_mfma_f32_16x16x32_bf16(a, wxh[ks][nt], acc[nt], 0, 0, 0);
        }
        // resident hh ksteps
        const int hbase = (ln << 9) + (qa << 3);
        #pragma unroll
        for (int ks = 0; ks < RKS; ++ks) {
            bf16x8 a = *(const bf16x8*)&hb_r[hbase + ((ks ^ kx) << 5)];
            #pragma unroll
            for (int nt = 0; nt < NT; ++nt)
                acc[nt] = __builtin_amdgcn_mfma_f32_16x16x32_bf16(a, whh[ks][nt], acc[nt], 0, 0, 0);
        }
        // streamed hh ksteps, 2-deep pipeline
        #pragma unroll
        for (int ks = RKS; ks < KSH; ++ks) {
            const int s = (ks - RKS) & 1;
            bf16x8 a = *(const bf16x8*)&hb_r[hbase + ((ks ^ kx) << 5)];
            #pragma unroll
            for (int nt = 0; nt < NT; ++nt)
                acc[nt] = __builtin_amdgcn_mfma_f32_16x16x32_bf16(a, sB[s][nt], acc[nt], 0, 0, 0);
            if (ks + 2 < KSH) {
                #pragma unroll
                for (int nt = 0; nt < NT; ++nt)
                    sB[s][nt] = *(const bf16x8*)(Wt + coff[nt] + ((ks + 2) << 5) + q8);
            }
        }
        // write h' : C/D layout col=ln, row=4q+i (all 16 rows real)
        #pragma unroll
        for (int nt = 0; nt < NT; ++nt) {
            const int cc = (wave << 3) + (nt << 1) + (ln >> 3);  // col>>3
            #pragma unroll
            for (int i = 0; i < 4; ++i) {
                const int row = (q << 2) + i;
                hb_w[(row << 9) + (((cc ^ (row & 7)) << 3) | (ln & 7))] =
                    (__bf16)fast_tanh(acc[nt][i]);
            }
        }
    };

    stage(0, xbuf[0]);
    __syncthreads();

    #pragma unroll 1
    for (int t = 0; t < T_LEN; t += 2) {
        stage(t + 1, xbuf[1]);                        // t+1 <= 79
        step(hbuf[0], xbuf[0], hbuf[1]);
        __syncthreads();
        if (t + 2 < T_LEN) stage(t + 2, xbuf[0]);
        step(hbuf[1], xbuf[1], hbuf[0]);
        __syncthreads();
    }
    // h_last in hbuf[0], rows 0..15

    // output head: wave w reduces rows w and w+8
    #pragma unroll
    for (int rr = 0; rr < 2; ++rr) {
        const int m = wave + (rr << 3);
        const bf16x8 hv = *(const bf16x8*)&hbuf[0][(m << 9) + ((lane ^ wave) << 3)];
        float s = 0.0f;
        #pragma unroll
        for (int j = 0; j < 8; ++j)
            s += (float)hv[j] * Wout[(lane << 3) + j];
        #pragma unroll
        for (int off = 32; off > 0; off >>= 1)
            s += __shfl_down(s, off, 64);
        if (lane == 0) {
            const float logit = s + bout[0];
            out[r0 + m] = __builtin_amdgcn_rcpf(
                1.0f + __builtin_amdgcn_exp2f(-logit * 1.4426950408889634f));
        }
    }
}

extern "C" void kernel_launch(void* const* d_in, const int* in_sizes, int n_in,
                              void* d_out, int out_size, void* d_ws, size_t ws_size,
                              hipStream_t stream) {
    __bf16* Wt = (__bf16*)d_ws;                 // 512*512*2 = 512 KB
    __bf16* Xt = Wt + UNITS * UNITS;            // 512*128*2 = 128 KB
    prep_kernel<<<dim3(320), dim3(256), 0, stream>>>(
        (const float*)d_in[3],   // W_hh
        (const float*)d_in[2],   // W_xh
        Wt, Xt);
    rnn_kernel<<<dim3(NBLK), dim3(NTHR), 0, stream>>>(
        (const int*)d_in[0],     // inputs
        (const float*)d_in[1],   // emb_table
        (const float*)d_in[4],   // b_h
        (const float*)d_in[5],   // W_out
        (const float*)d_in[6],   // b_out
        Wt, Xt,
        (float*)d_out);
}